// Round 8
// baseline (114.305 us; speedup 1.0000x reference)
//
#include <hip/hip_runtime.h>
#include <cstdint>
#include <cstddef>

#define BATCH 32
#define IMH 512
#define IMW 512
#define KMAX 256
#define NB 4096          // histogram bins: key bits [63:52]

// K1: register rolling-window NMS. Wave = 256 cols (4/lane), RPW output rows.
#define RPW 8
#define NBLKX 2
#define NBLKY 16
#define NBLK (NBLKX * NBLKY)   // 32 blocks/image
#define LCAP 2048              // block covers 256x32 px; strict maxima <= 1/4 = 2048 (no overflow)

// tail kernel LDS caps
#define SKEYS 5120             // in-bin* keys (40 KB)

typedef unsigned long long u64;

__device__ __forceinline__ float sigmoidf_(float x) {
    return 1.0f / (1.0f + expf(-x));
}
__device__ __forceinline__ float scoref_(float r, float u) {
    const float sg = sigmoidf_(r);
    return sg * sg * (1.0f - 0.35f * sigmoidf_(u));
}

// ---------------------------------------------------------------------------
// K1: fused score + 3x3 NMS, register rolling window (no score LDS, no global
// atomics). Each block writes its candidates to a FIXED segment
// cand[b][blk][LCAP] and plain-stores the count to blkcnt[b][blk] — no
// pre-zeroed state anywhere.
// key = (score_bits<<32) | ~idx -> unsigned desc == (score desc, idx asc),
// matching lax.top_k's stable tie-break.
// ---------------------------------------------------------------------------
__global__ __launch_bounds__(256)
void score_nms_kernel(const float* __restrict__ route,
                      const float* __restrict__ unc,
                      u64* __restrict__ cand,
                      int* __restrict__ blkcnt) {
    const int b    = blockIdx.z;
    const int tid  = threadIdx.x;
    const int w    = tid >> 6;
    const int lane = tid & 63;
    const int y0   = (blockIdx.y * 4 + w) * RPW;
    const int x0   = blockIdx.x * 256 + lane * 4;
    const int blk  = blockIdx.y * NBLKX + blockIdx.x;

    __shared__ u64 lcand[LCAP];
    __shared__ int lcnt;
    if (tid == 0) lcnt = 0;
    __syncthreads();

    const float* rB = route + (size_t)b * IMH * IMW;
    const float* uB = unc   + (size_t)b * IMH * IMW;

    // wave-edge column owned by this lane (one lane per side per wave)
    int ex = -1;
    if (lane == 0)       ex = x0 - 1;
    else if (lane == 63) ex = x0 + 4;
    const bool eAct = (ex >= 0 && ex < IMW);

    const u64 laneMaskLt = (1ull << lane) - 1ull;

    float sP[4], hP1[4], hP2[4];
    #pragma unroll
    for (int j = 0; j < 4; ++j) { sP[j] = -INFINITY; hP1[j] = -INFINITY; hP2[j] = -INFINITY; }

    const int ylast = y0 + RPW;
    bool v = (y0 - 1 >= 0);
    float4 r4, u4; float er = 0.f, eu = 0.f;
    if (v) {
        r4 = *(const float4*)(rB + (size_t)(y0 - 1) * IMW + x0);
        u4 = *(const float4*)(uB + (size_t)(y0 - 1) * IMW + x0);
        if (eAct) { er = rB[(size_t)(y0 - 1) * IMW + ex]; eu = uB[(size_t)(y0 - 1) * IMW + ex]; }
    }

    for (int y = y0 - 1; y <= ylast; ++y) {
        const int yn = y + 1;
        const bool vn = (yn <= ylast) && (yn < IMH);
        float4 r4n, u4n; float ern = 0.f, eun = 0.f;
        if (vn) {
            r4n = *(const float4*)(rB + (size_t)yn * IMW + x0);
            u4n = *(const float4*)(uB + (size_t)yn * IMW + x0);
            if (eAct) { ern = rB[(size_t)yn * IMW + ex]; eun = uB[(size_t)yn * IMW + ex]; }
        }

        float sC[4], hmC[4];
        float es = -INFINITY;
        if (v && eAct) es = scoref_(er, eu);
        if (v) {
            sC[0] = scoref_(r4.x, u4.x);
            sC[1] = scoref_(r4.y, u4.y);
            sC[2] = scoref_(r4.z, u4.z);
            sC[3] = scoref_(r4.w, u4.w);
        } else {
            sC[0] = sC[1] = sC[2] = sC[3] = -INFINITY;
        }
        float lft = __shfl_up(sC[3], 1, 64);
        if (lane == 0) lft = es;
        float rgt = __shfl_down(sC[0], 1, 64);
        if (lane == 63) rgt = es;
        if (v) {
            hmC[0] = fmaxf(fmaxf(lft,   sC[0]), sC[1]);
            hmC[1] = fmaxf(fmaxf(sC[0], sC[1]), sC[2]);
            hmC[2] = fmaxf(fmaxf(sC[1], sC[2]), sC[3]);
            hmC[3] = fmaxf(fmaxf(sC[2], sC[3]), rgt);
        } else {
            hmC[0] = hmC[1] = hmC[2] = hmC[3] = -INFINITY;
        }

        if (y >= y0 + 1) {
            const int yo = y - 1;
            bool p[4]; int cntT = 0;
            #pragma unroll
            for (int j = 0; j < 4; ++j) {
                const float m9 = fmaxf(fmaxf(hP2[j], hP1[j]), hmC[j]);
                p[j] = (sP[j] >= m9);
                cntT += p[j] ? 1 : 0;
            }
            const u64 B0 = __ballot(cntT & 1);
            const u64 B1 = __ballot(cntT & 2);
            const u64 B2 = __ballot(cntT & 4);
            const int total = __popcll(B0) + 2 * __popcll(B1) + 4 * __popcll(B2);
            if (total > 0) {
                const int prefix = __popcll(B0 & laneMaskLt) + 2 * __popcll(B1 & laneMaskLt)
                                 + 4 * __popcll(B2 & laneMaskLt);
                int wbase = 0;
                if (lane == 0) wbase = atomicAdd(&lcnt, total);
                wbase = __shfl(wbase, 0, 64);
                int mb = wbase + prefix;
                #pragma unroll
                for (int j = 0; j < 4; ++j) {
                    if (p[j]) {
                        const unsigned idx = (unsigned)(yo * IMW + (x0 + j));
                        const u64 key = ((u64)__float_as_uint(sP[j]) << 32) | (unsigned)(~idx);
                        if (mb < LCAP) lcand[mb] = key;
                        ++mb;
                    }
                }
            }
        }

        #pragma unroll
        for (int j = 0; j < 4; ++j) { hP2[j] = hP1[j]; hP1[j] = hmC[j]; sP[j] = sC[j]; }
        r4 = r4n; u4 = u4n; er = ern; eu = eun; v = vn;
    }

    __syncthreads();
    const int m = (lcnt < LCAP) ? lcnt : LCAP;
    u64* seg = cand + ((size_t)b * NBLK + blk) * LCAP;
    for (int i = tid; i < m; i += 256) seg[i] = lcand[i];
    if (tid == 0) blkcnt[b * NBLK + blk] = m;
}

// ---------------------------------------------------------------------------
// K2 (fused tail): 1 block/image, no cross-block deps, no global atomics.
//   scan 1: 4096-bin LDS histogram of key top-12 bits over all segments
//   derive exact threshold bin bstar + above-count in-block
//   scan 2: split keys (bin>bstar -> sel, bin==bstar -> skeys)
//   13-nibble radix-select (prefix bstar known) -> exact threshold key T
//   collect, bitonic sort desc, ROI epilogue
// ---------------------------------------------------------------------------
__global__ __launch_bounds__(256)
void topk_tail_kernel(const u64* __restrict__ cand,
                      const int* __restrict__ blkcnt,
                      const float* __restrict__ scale,
                      const float* __restrict__ unc,
                      const int* __restrict__ imh,
                      const int* __restrict__ imw,
                      float* __restrict__ rois,
                      float* __restrict__ scoresOut,
                      float* __restrict__ validOut) {
    const int b   = blockIdx.x;
    const int tid = threadIdx.x;

    __shared__ unsigned hist[NB];          // 16 KB
    __shared__ u64 skeys[SKEYS];           // 40 KB
    __shared__ u64 sel[KMAX];              // 2 KB
    __shared__ unsigned sA[256], csS[256]; // 2 KB
    __shared__ unsigned h2[16];
    __shared__ u64 prefS;
    __shared__ int segc[NBLK];
    __shared__ int bstarS, rem2S, cSel, cSk;

    if (tid < NBLK) segc[tid] = blkcnt[b * NBLK + tid];
    for (int i = tid; i < NB; i += 256) hist[i] = 0;
    sel[tid] = 0ull;
    if (tid == 0) { bstarS = 0; cSel = 0; cSk = 0; }
    __syncthreads();

    const u64* cb = cand + (size_t)b * NBLK * LCAP;

    // ---- scan 1: histogram ----
    for (int blk = 0; blk < NBLK; ++blk) {
        const int c = segc[blk];
        const u64* seg = cb + (size_t)blk * LCAP;
        for (int i = tid; i < c; i += 256)
            atomicAdd(&hist[(unsigned)(seg[i] >> 52)], 1u);
    }
    __syncthreads();

    // ---- derive bstar (exact threshold bin) ----
    unsigned cs = 0;
    #pragma unroll
    for (int j = 0; j < 16; ++j) cs += hist[tid * 16 + j];
    csS[tid] = cs;
    sA[tid]  = cs;
    __syncthreads();
    for (int off = 1; off < 256; off <<= 1) {
        const unsigned vv = sA[tid] + ((tid + off < 256) ? sA[tid + off] : 0u);
        __syncthreads();
        sA[tid] = vv;
        __syncthreads();
    }
    const unsigned total = sA[0];
    if (total > (unsigned)KMAX) {
        const unsigned incl = sA[tid];
        const unsigned excl = incl - csS[tid];
        if (excl < (unsigned)KMAX && incl >= (unsigned)KMAX) {
            unsigned acc = excl;
            int bbin = tid * 16 + 15;
            for (; bbin > tid * 16; --bbin) {
                const unsigned h = hist[bbin];
                if (acc + h >= (unsigned)KMAX) break;
                acc += h;
            }
            bstarS = bbin;
        }
    }
    __syncthreads();
    const unsigned bstar = (unsigned)bstarS;

    // ---- scan 2: split ----
    for (int blk = 0; blk < NBLK; ++blk) {
        const int c = segc[blk];
        const u64* seg = cb + (size_t)blk * LCAP;
        for (int i = tid; i < c; i += 256) {
            const u64 k = seg[i];
            const unsigned bin = (unsigned)(k >> 52);
            if (bin > bstar) {
                const int p = atomicAdd(&cSel, 1);
                if (p < KMAX) sel[p] = k;
            } else if (bin == bstar) {
                const int p = atomicAdd(&cSk, 1);
                if (p < SKEYS) skeys[p] = k;
            }
        }
    }
    __syncthreads();
    const int above = cSel;
    int nk = cSk;
    if (nk > SKEYS) nk = SKEYS;
    const int remk = KMAX - above;

    // ---- radix-select over skeys' low 13 nibbles ----
    u64 T = 0;
    if (nk > remk) {
        if (tid == 0) { prefS = (u64)bstar; rem2S = remk; }
        __syncthreads();
        for (int p = 12; p >= 0; --p) {
            if (tid < 16) h2[tid] = 0;
            __syncthreads();
            const u64 pre = prefS;
            for (int i = tid; i < nk; i += 256) {
                const u64 k = skeys[i];
                if ((k >> ((p + 1) * 4)) == pre)
                    atomicAdd(&h2[(unsigned)(k >> (p * 4)) & 15u], 1u);
            }
            __syncthreads();
            if (tid == 0) {
                int rem = rem2S;
                int vv;
                for (vv = 15; vv >= 0; --vv) {
                    const int hv = (int)h2[vv];
                    if (rem <= hv) break;
                    rem -= hv;
                }
                if (vv < 0) vv = 0;
                prefS = (pre << 4) | (unsigned)vv;
                rem2S = rem;
            }
            __syncthreads();
        }
        T = prefS;
    }

    for (int i = tid; i < nk; i += 256) {
        const u64 k = skeys[i];
        if (k >= T) {
            const int p = atomicAdd(&cSel, 1);
            if (p < KMAX) sel[p] = k;
        }
    }
    __syncthreads();

    // ---- bitonic sort descending (keys unique; zeros sink) ----
    for (int kk = 2; kk <= KMAX; kk <<= 1) {
        for (int j = kk >> 1; j > 0; j >>= 1) {
            const int ixj = tid ^ j;
            if (ixj > tid) {
                const u64 a  = sel[tid];
                const u64 bb = sel[ixj];
                const bool desc = ((tid & kk) == 0);
                if (desc ? (a < bb) : (a > bb)) {
                    sel[tid] = bb;
                    sel[ixj] = a;
                }
            }
            __syncthreads();
        }
    }

    // ---- epilogue ----
    const u64 k = sel[tid];
    const float value = __uint_as_float((unsigned)(k >> 32));
    const bool valid  = (k != 0ull) && (value > 0.0f);

    float r0 = 0.f, r1 = 0.f, r2 = 0.f, r3 = 0.f, r4 = 0.f, sv = 0.f, vv = 0.f;
    if (valid) {
        const unsigned idx = ~(unsigned)(k & 0xFFFFFFFFull);
        const int y = (int)(idx / IMW);
        const int x = (int)(idx % IMW);
        const float cx = ((float)x + 0.5f) * 4.0f;
        const float cy = ((float)y + 0.5f) * 4.0f;
        const float sg = scale[(size_t)b * IMH * IMW + idx];
        const float uu = unc[(size_t)b * IMH * IMW + idx];
        const float su = sigmoidf_(uu);
        float side = 32.0f + sigmoidf_(sg) * (512.0f - 32.0f);
        side = side * (1.0f + 0.25f * su);
        const float half = side * 0.5f;
        const float fw = (float)imw[0];
        const float fh = (float)imh[0];
        r0 = (float)b;
        r1 = fminf(fmaxf(cx - half, 0.0f), fw - 1.0f);
        r2 = fminf(fmaxf(cy - half, 0.0f), fh - 1.0f);
        r3 = fminf(fmaxf(cx + half, 1.0f), fw);
        r4 = fminf(fmaxf(cy + half, 1.0f), fh);
        sv = value;
        vv = 1.0f;
    }
    float* roiP = rois + ((size_t)b * KMAX + tid) * 5;
    roiP[0] = r0; roiP[1] = r1; roiP[2] = r2; roiP[3] = r3; roiP[4] = r4;
    scoresOut[b * KMAX + tid] = sv;
    validOut[b * KMAX + tid]  = vv;
}

extern "C" void kernel_launch(void* const* d_in, const int* in_sizes, int n_in,
                              void* d_out, int out_size, void* d_ws, size_t ws_size,
                              hipStream_t stream) {
    const float* route = (const float*)d_in[0];
    const float* scale = (const float*)d_in[1];
    const float* unc   = (const float*)d_in[2];
    const int*   imh   = (const int*)d_in[3];
    const int*   imw   = (const int*)d_in[4];

    // ws layout (~16.8 MB): [cand B*NBLK*LCAP u64][blkcnt B*NBLK int]
    char* ws = (char*)d_ws;
    u64* cand   = (u64*)ws;
    int* blkcnt = (int*)(ws + (size_t)BATCH * NBLK * LCAP * sizeof(u64));

    float* rois      = (float*)d_out;                       // [B, 256, 5]
    float* scoresOut = rois + (size_t)BATCH * KMAX * 5;     // [B, 256]
    float* validOut  = scoresOut + (size_t)BATCH * KMAX;    // [B, 256]

    dim3 grid1(NBLKX, NBLKY, BATCH);       // 256-col half, 4-wave row group, image
    score_nms_kernel<<<grid1, 256, 0, stream>>>(route, unc, cand, blkcnt);

    topk_tail_kernel<<<BATCH, 256, 0, stream>>>(cand, blkcnt, scale, unc,
                                                imh, imw, rois, scoresOut, validOut);
}

// Round 9
// 74.813 us; speedup vs baseline: 1.5279x; 1.5279x over previous
//
#include <hip/hip_runtime.h>
#include <cstdint>
#include <cstddef>

#define BATCH 32
#define IMH 512
#define IMW 512
#define KMAX 256
#define NB 4096          // histogram bins: key bits [63:52]
#define NSLICE 8
#define SEG_PER_SLICE 4  // NBLK / NSLICE

// K1: register rolling-window NMS. Wave = 256 cols (4/lane), RPW output rows.
#define RPW 8
#define NBLKX 2
#define NBLKY 16
#define NBLK (NBLKX * NBLKY)   // 32 blocks/image
#define LCAP 2048              // 256x32 tile: strict maxima <= 2048 (worst-case proof)

#define SLCAP 512              // per-(image,slice) survivor segment
#define SKEYS 5120             // finalize LDS cap for in-bin* keys
#define SURV_MAX (NSLICE * SLCAP)

typedef unsigned long long u64;
typedef unsigned short u16;

__device__ __forceinline__ float sigmoidf_(float x) {
    return 1.0f / (1.0f + expf(-x));
}
__device__ __forceinline__ float scoref_(float r, float u) {
    const float sg = sigmoidf_(r);
    return sg * sg * (1.0f - 0.35f * sigmoidf_(u));
}

// ---------------------------------------------------------------------------
// K1: fused score + 3x3 NMS, register rolling window. Fixed per-block output
// segment cand[b][blk][LCAP] + plain-stored count. No pre-zeroed state.
// key = (score_bits<<32) | ~idx -> unsigned desc == (score desc, idx asc).
// ---------------------------------------------------------------------------
__global__ __launch_bounds__(256)
void score_nms_kernel(const float* __restrict__ route,
                      const float* __restrict__ unc,
                      u64* __restrict__ cand,
                      int* __restrict__ blkcnt) {
    const int b    = blockIdx.z;
    const int tid  = threadIdx.x;
    const int w    = tid >> 6;
    const int lane = tid & 63;
    const int y0   = (blockIdx.y * 4 + w) * RPW;
    const int x0   = blockIdx.x * 256 + lane * 4;
    const int blk  = blockIdx.y * NBLKX + blockIdx.x;

    __shared__ u64 lcand[LCAP];
    __shared__ int lcnt;
    if (tid == 0) lcnt = 0;
    __syncthreads();

    const float* rB = route + (size_t)b * IMH * IMW;
    const float* uB = unc   + (size_t)b * IMH * IMW;

    int ex = -1;
    if (lane == 0)       ex = x0 - 1;
    else if (lane == 63) ex = x0 + 4;
    const bool eAct = (ex >= 0 && ex < IMW);

    const u64 laneMaskLt = (1ull << lane) - 1ull;

    float sP[4], hP1[4], hP2[4];
    #pragma unroll
    for (int j = 0; j < 4; ++j) { sP[j] = -INFINITY; hP1[j] = -INFINITY; hP2[j] = -INFINITY; }

    const int ylast = y0 + RPW;
    bool v = (y0 - 1 >= 0);
    float4 r4, u4; float er = 0.f, eu = 0.f;
    if (v) {
        r4 = *(const float4*)(rB + (size_t)(y0 - 1) * IMW + x0);
        u4 = *(const float4*)(uB + (size_t)(y0 - 1) * IMW + x0);
        if (eAct) { er = rB[(size_t)(y0 - 1) * IMW + ex]; eu = uB[(size_t)(y0 - 1) * IMW + ex]; }
    }

    for (int y = y0 - 1; y <= ylast; ++y) {
        const int yn = y + 1;
        const bool vn = (yn <= ylast) && (yn < IMH);
        float4 r4n, u4n; float ern = 0.f, eun = 0.f;
        if (vn) {
            r4n = *(const float4*)(rB + (size_t)yn * IMW + x0);
            u4n = *(const float4*)(uB + (size_t)yn * IMW + x0);
            if (eAct) { ern = rB[(size_t)yn * IMW + ex]; eun = uB[(size_t)yn * IMW + ex]; }
        }

        float sC[4], hmC[4];
        float es = -INFINITY;
        if (v && eAct) es = scoref_(er, eu);
        if (v) {
            sC[0] = scoref_(r4.x, u4.x);
            sC[1] = scoref_(r4.y, u4.y);
            sC[2] = scoref_(r4.z, u4.z);
            sC[3] = scoref_(r4.w, u4.w);
        } else {
            sC[0] = sC[1] = sC[2] = sC[3] = -INFINITY;
        }
        float lft = __shfl_up(sC[3], 1, 64);
        if (lane == 0) lft = es;
        float rgt = __shfl_down(sC[0], 1, 64);
        if (lane == 63) rgt = es;
        if (v) {
            hmC[0] = fmaxf(fmaxf(lft,   sC[0]), sC[1]);
            hmC[1] = fmaxf(fmaxf(sC[0], sC[1]), sC[2]);
            hmC[2] = fmaxf(fmaxf(sC[1], sC[2]), sC[3]);
            hmC[3] = fmaxf(fmaxf(sC[2], sC[3]), rgt);
        } else {
            hmC[0] = hmC[1] = hmC[2] = hmC[3] = -INFINITY;
        }

        if (y >= y0 + 1) {
            const int yo = y - 1;
            bool p[4]; int cntT = 0;
            #pragma unroll
            for (int j = 0; j < 4; ++j) {
                const float m9 = fmaxf(fmaxf(hP2[j], hP1[j]), hmC[j]);
                p[j] = (sP[j] >= m9);
                cntT += p[j] ? 1 : 0;
            }
            const u64 B0 = __ballot(cntT & 1);
            const u64 B1 = __ballot(cntT & 2);
            const u64 B2 = __ballot(cntT & 4);
            const int total = __popcll(B0) + 2 * __popcll(B1) + 4 * __popcll(B2);
            if (total > 0) {
                const int prefix = __popcll(B0 & laneMaskLt) + 2 * __popcll(B1 & laneMaskLt)
                                 + 4 * __popcll(B2 & laneMaskLt);
                int wbase = 0;
                if (lane == 0) wbase = atomicAdd(&lcnt, total);
                wbase = __shfl(wbase, 0, 64);
                int mb = wbase + prefix;
                #pragma unroll
                for (int j = 0; j < 4; ++j) {
                    if (p[j]) {
                        const unsigned idx = (unsigned)(yo * IMW + (x0 + j));
                        const u64 key = ((u64)__float_as_uint(sP[j]) << 32) | (unsigned)(~idx);
                        if (mb < LCAP) lcand[mb] = key;
                        ++mb;
                    }
                }
            }
        }

        #pragma unroll
        for (int j = 0; j < 4; ++j) { hP2[j] = hP1[j]; hP1[j] = hmC[j]; sP[j] = sC[j]; }
        r4 = r4n; u4 = u4n; er = ern; eu = eun; v = vn;
    }

    __syncthreads();
    const int m = (lcnt < LCAP) ? lcnt : LCAP;
    u64* seg = cand + ((size_t)b * NBLK + blk) * LCAP;
    for (int i = tid; i < m; i += 256) seg[i] = lcand[i];
    if (tid == 0) blkcnt[b * NBLK + blk] = m;
}

// ---------------------------------------------------------------------------
// K2: (slice, image). Block histograms its 4 candidate segments into LDS,
// plain-stores u16 slicehist[b][s][4096]. No global atomics, no memset.
// ---------------------------------------------------------------------------
__global__ __launch_bounds__(256)
void slice_hist_kernel(const u64* __restrict__ cand,
                       const int* __restrict__ blkcnt,
                       u16* __restrict__ slicehist) {
    const int s   = blockIdx.x;
    const int b   = blockIdx.y;
    const int tid = threadIdx.x;

    __shared__ unsigned hist[NB];
    for (int i = tid; i < NB; i += 256) hist[i] = 0;
    __syncthreads();

    for (int q = 0; q < SEG_PER_SLICE; ++q) {
        const int blk = s * SEG_PER_SLICE + q;
        const int c = blkcnt[b * NBLK + blk];
        const u64* seg = cand + ((size_t)b * NBLK + blk) * LCAP;
        for (int i = tid; i < c; i += 256)
            atomicAdd(&hist[(unsigned)(seg[i] >> 52)], 1u);
    }
    __syncthreads();

    u16* out = slicehist + (((size_t)b * NSLICE + s) << 12);
    for (int i = tid; i < NB; i += 256) out[i] = (u16)hist[i];
}

// ---------------------------------------------------------------------------
// K3: 1 block/image. Merge 8 slice hists, suffix-scan -> exact threshold bin
// bstar, publish meta[b].
// ---------------------------------------------------------------------------
__global__ __launch_bounds__(256)
void merge_meta_kernel(const u16* __restrict__ slicehist,
                       int* __restrict__ meta) {
    const int b   = blockIdx.x;
    const int tid = threadIdx.x;

    __shared__ unsigned tot[NB];
    __shared__ unsigned sA[256], csS[256];
    __shared__ int bstarS;

    const u16* shB = slicehist + (((size_t)b * NSLICE) << 12);
    for (int i = tid; i < NB; i += 256) {
        unsigned t = 0;
        #pragma unroll
        for (int s = 0; s < NSLICE; ++s) t += shB[(s << 12) + i];
        tot[i] = t;
    }
    if (tid == 0) bstarS = 0;
    __syncthreads();

    unsigned cs = 0;
    #pragma unroll
    for (int j = 0; j < 16; ++j) cs += tot[tid * 16 + j];
    csS[tid] = cs;
    sA[tid]  = cs;
    __syncthreads();
    for (int off = 1; off < 256; off <<= 1) {
        const unsigned vv = sA[tid] + ((tid + off < 256) ? sA[tid + off] : 0u);
        __syncthreads();
        sA[tid] = vv;
        __syncthreads();
    }
    const unsigned total = sA[0];
    if (total > (unsigned)KMAX) {
        const unsigned incl = sA[tid];
        const unsigned excl = incl - csS[tid];
        if (excl < (unsigned)KMAX && incl >= (unsigned)KMAX) {
            unsigned acc = excl;
            int bbin = tid * 16 + 15;
            for (; bbin > tid * 16; --bbin) {
                const unsigned h = tot[bbin];
                if (acc + h >= (unsigned)KMAX) break;
                acc += h;
            }
            bstarS = bbin;
        }
    }
    __syncthreads();
    if (tid == 0) meta[b] = bstarS;
}

// ---------------------------------------------------------------------------
// K4: (slice, image). Compact the slice's 4 segments (bin >= bstar) into a
// fixed survivor segment surv[b][s][SLCAP] + plain-stored count.
// ---------------------------------------------------------------------------
__global__ __launch_bounds__(256)
void compact_kernel(const u64* __restrict__ cand,
                    const int* __restrict__ blkcnt,
                    const int* __restrict__ meta,
                    u64* __restrict__ surv,
                    int* __restrict__ scount) {
    const int s    = blockIdx.x;
    const int b    = blockIdx.y;
    const int tid  = threadIdx.x;
    const int lane = tid & 63;

    __shared__ u64 lbuf[SLCAP];
    __shared__ int lcnt2;

    const unsigned bstar = (unsigned)meta[b];
    if (tid == 0) lcnt2 = 0;
    __syncthreads();

    for (int q = 0; q < SEG_PER_SLICE; ++q) {
        const int blk = s * SEG_PER_SLICE + q;
        const int c = blkcnt[b * NBLK + blk];
        const u64* seg = cand + ((size_t)b * NBLK + blk) * LCAP;
        for (int i = tid; i < c; i += 256) {
            const u64 k = seg[i];
            const bool pred = ((unsigned)(k >> 52) >= bstar);
            const u64 mb = __ballot(pred);
            if (mb) {
                const int leader = __ffsll(mb) - 1;
                const int wcount = __popcll(mb);
                const int prefix = __popcll(mb & ((1ull << lane) - 1));
                int wb_ = 0;
                if (lane == leader) wb_ = atomicAdd(&lcnt2, wcount);
                wb_ = __shfl(wb_, leader, 64);
                if (pred) {
                    const int pos = wb_ + prefix;
                    if (pos < SLCAP) lbuf[pos] = k;
                }
            }
        }
    }
    __syncthreads();
    int m = lcnt2;
    if (m > SLCAP) m = SLCAP;
    u64* out = surv + (((size_t)b * NSLICE + s)) * SLCAP;
    for (int i = tid; i < m; i += 256) out[i] = lbuf[i];
    if (tid == 0) scount[b * NSLICE + s] = m;
}

// ---------------------------------------------------------------------------
// K5: 1 block/image over ~600 survivors. Split (bin>bstar -> sel; == -> skeys);
// 13-nibble radix-select (prefix bstar known) -> exact threshold key T;
// collect; bitonic sort desc; ROI epilogue.
// ---------------------------------------------------------------------------
__global__ __launch_bounds__(256)
void finalize_kernel(const u64* __restrict__ surv,
                     const int* __restrict__ scount,
                     const int* __restrict__ meta,
                     const float* __restrict__ scale,
                     const float* __restrict__ unc,
                     const int* __restrict__ imh,
                     const int* __restrict__ imw,
                     float* __restrict__ rois,
                     float* __restrict__ scoresOut,
                     float* __restrict__ validOut) {
    const int b   = blockIdx.x;
    const int tid = threadIdx.x;

    __shared__ u64 skeys[SKEYS];
    __shared__ u64 sel[KMAX];
    __shared__ unsigned h2[16];
    __shared__ u64 prefS;
    __shared__ int sc_s[NSLICE];
    __shared__ int rem2S, cSel, cSk;

    const unsigned bstar = (unsigned)meta[b];
    if (tid < NSLICE) sc_s[tid] = scount[b * NSLICE + tid];
    sel[tid] = 0ull;
    if (tid == 0) { cSel = 0; cSk = 0; }
    __syncthreads();

    for (int s = 0; s < NSLICE; ++s) {
        const int c = sc_s[s];
        const u64* seg = surv + ((size_t)b * NSLICE + s) * SLCAP;
        for (int i = tid; i < c; i += 256) {
            const u64 k = seg[i];
            if ((unsigned)(k >> 52) > bstar) {
                const int p = atomicAdd(&cSel, 1);
                if (p < KMAX) sel[p] = k;
            } else {
                const int p = atomicAdd(&cSk, 1);
                if (p < SKEYS) skeys[p] = k;
            }
        }
    }
    __syncthreads();
    const int above = cSel;
    int nk = cSk;
    if (nk > SKEYS) nk = SKEYS;
    const int remk = KMAX - above;

    u64 T = 0;
    if (nk > remk) {
        if (tid == 0) { prefS = (u64)bstar; rem2S = remk; }
        __syncthreads();
        for (int p = 12; p >= 0; --p) {
            if (tid < 16) h2[tid] = 0;
            __syncthreads();
            const u64 pre = prefS;
            for (int i = tid; i < nk; i += 256) {
                const u64 k = skeys[i];
                if ((k >> ((p + 1) * 4)) == pre)
                    atomicAdd(&h2[(unsigned)(k >> (p * 4)) & 15u], 1u);
            }
            __syncthreads();
            if (tid == 0) {
                int rem = rem2S;
                int vv;
                for (vv = 15; vv >= 0; --vv) {
                    const int hv = (int)h2[vv];
                    if (rem <= hv) break;
                    rem -= hv;
                }
                if (vv < 0) vv = 0;
                prefS = (pre << 4) | (unsigned)vv;
                rem2S = rem;
            }
            __syncthreads();
        }
        T = prefS;
    }

    for (int i = tid; i < nk; i += 256) {
        const u64 k = skeys[i];
        if (k >= T) {
            const int p = atomicAdd(&cSel, 1);
            if (p < KMAX) sel[p] = k;
        }
    }
    __syncthreads();

    // bitonic sort descending (keys unique; zeros sink)
    for (int kk = 2; kk <= KMAX; kk <<= 1) {
        for (int j = kk >> 1; j > 0; j >>= 1) {
            const int ixj = tid ^ j;
            if (ixj > tid) {
                const u64 a  = sel[tid];
                const u64 bb = sel[ixj];
                const bool desc = ((tid & kk) == 0);
                if (desc ? (a < bb) : (a > bb)) {
                    sel[tid] = bb;
                    sel[ixj] = a;
                }
            }
            __syncthreads();
        }
    }

    // epilogue
    const u64 k = sel[tid];
    const float value = __uint_as_float((unsigned)(k >> 32));
    const bool valid  = (k != 0ull) && (value > 0.0f);

    float r0 = 0.f, r1 = 0.f, r2 = 0.f, r3 = 0.f, r4 = 0.f, sv = 0.f, vv = 0.f;
    if (valid) {
        const unsigned idx = ~(unsigned)(k & 0xFFFFFFFFull);
        const int y = (int)(idx / IMW);
        const int x = (int)(idx % IMW);
        const float cx = ((float)x + 0.5f) * 4.0f;
        const float cy = ((float)y + 0.5f) * 4.0f;
        const float sg = scale[(size_t)b * IMH * IMW + idx];
        const float uu = unc[(size_t)b * IMH * IMW + idx];
        const float su = sigmoidf_(uu);
        float side = 32.0f + sigmoidf_(sg) * (512.0f - 32.0f);
        side = side * (1.0f + 0.25f * su);
        const float half = side * 0.5f;
        const float fw = (float)imw[0];
        const float fh = (float)imh[0];
        r0 = (float)b;
        r1 = fminf(fmaxf(cx - half, 0.0f), fw - 1.0f);
        r2 = fminf(fmaxf(cy - half, 0.0f), fh - 1.0f);
        r3 = fminf(fmaxf(cx + half, 1.0f), fw);
        r4 = fminf(fmaxf(cy + half, 1.0f), fh);
        sv = value;
        vv = 1.0f;
    }
    float* roiP = rois + ((size_t)b * KMAX + tid) * 5;
    roiP[0] = r0; roiP[1] = r1; roiP[2] = r2; roiP[3] = r3; roiP[4] = r4;
    scoresOut[b * KMAX + tid] = sv;
    validOut[b * KMAX + tid]  = vv;
}

extern "C" void kernel_launch(void* const* d_in, const int* in_sizes, int n_in,
                              void* d_out, int out_size, void* d_ws, size_t ws_size,
                              hipStream_t stream) {
    const float* route = (const float*)d_in[0];
    const float* scale = (const float*)d_in[1];
    const float* unc   = (const float*)d_in[2];
    const int*   imh   = (const int*)d_in[3];
    const int*   imw   = (const int*)d_in[4];

    // ws layout (~20 MB):
    // [cand 16.78MB][blkcnt 4KB][slicehist u16 2MB][surv 1MB][scount 1KB][meta 128B]
    char* ws = (char*)d_ws;
    u64* cand   = (u64*)ws;
    size_t off  = (size_t)BATCH * NBLK * LCAP * sizeof(u64);
    int* blkcnt = (int*)(ws + off);                 off += (size_t)BATCH * NBLK * sizeof(int);
    u16* slicehist = (u16*)(ws + off);              off += (size_t)BATCH * NSLICE * NB * sizeof(u16);
    u64* surv   = (u64*)(ws + off);                 off += (size_t)BATCH * NSLICE * SLCAP * sizeof(u64);
    int* scount = (int*)(ws + off);                 off += (size_t)BATCH * NSLICE * sizeof(int);
    int* meta   = (int*)(ws + off);

    float* rois      = (float*)d_out;                       // [B, 256, 5]
    float* scoresOut = rois + (size_t)BATCH * KMAX * 5;     // [B, 256]
    float* validOut  = scoresOut + (size_t)BATCH * KMAX;    // [B, 256]

    dim3 grid1(NBLKX, NBLKY, BATCH);
    score_nms_kernel<<<grid1, 256, 0, stream>>>(route, unc, cand, blkcnt);

    dim3 grid2(NSLICE, BATCH);
    slice_hist_kernel<<<grid2, 256, 0, stream>>>(cand, blkcnt, slicehist);
    merge_meta_kernel<<<BATCH, 256, 0, stream>>>(slicehist, meta);
    compact_kernel<<<grid2, 256, 0, stream>>>(cand, blkcnt, meta, surv, scount);

    finalize_kernel<<<BATCH, 256, 0, stream>>>(surv, scount, meta, scale, unc,
                                               imh, imw, rois, scoresOut, validOut);
}